// Round 1
// baseline (458.686 us; speedup 1.0000x reference)
//
#include <hip/hip_runtime.h>
#include <math.h>

#define Bsz 2
#define Nn 2048
#define Dd 256
#define Hh 4
#define DHh 64
#define Jj 32
#define CE 274      // 2*EIN = 274
#define CEP 276     // padded to multiple of 4

__device__ __forceinline__ float4 ld4(const float* p) { return *reinterpret_cast<const float4*>(p); }

// ---------------------------------------------------------------------------
// K0: zero the coors_out region (atomics accumulate into it)
// ---------------------------------------------------------------------------
__global__ void k_zero(float* __restrict__ p, int n) {
    int i = blockIdx.x * 256 + threadIdx.x;
    if (i < n) p[i] = 0.f;
}

// ---------------------------------------------------------------------------
// K1: qkv = feats(4096x256) @ w_qkv(256x768) -> q,k,v each [b,h,n,64]
// grid (12, 64), block 256
// ---------------------------------------------------------------------------
__global__ __launch_bounds__(256) void k_qkv(const float* __restrict__ feats,
                                             const float* __restrict__ w,
                                             float* __restrict__ q,
                                             float* __restrict__ k,
                                             float* __restrict__ v) {
    __shared__ float As[32][68];
    __shared__ float Bs[32][68];
    const int t = threadIdx.x;
    const int bn = blockIdx.x * 64;   // col tile base (0..768)
    const int bm = blockIdx.y * 64;   // row tile base (0..4096)
    const int tn = t & 15, tm = t >> 4;
    const int ml = t >> 3, kl = (t & 7) << 2;
    const int kl2 = t >> 4, nl = (t & 15) << 2;
    float acc[4][4] = {};
    for (int k0 = 0; k0 < 256; k0 += 32) {
        float4 a0 = ld4(&feats[(size_t)(bm + ml) * 256 + k0 + kl]);
        float4 a1 = ld4(&feats[(size_t)(bm + ml + 32) * 256 + k0 + kl]);
        As[kl + 0][ml] = a0.x; As[kl + 1][ml] = a0.y; As[kl + 2][ml] = a0.z; As[kl + 3][ml] = a0.w;
        As[kl + 0][ml + 32] = a1.x; As[kl + 1][ml + 32] = a1.y; As[kl + 2][ml + 32] = a1.z; As[kl + 3][ml + 32] = a1.w;
        *reinterpret_cast<float4*>(&Bs[kl2][nl])      = ld4(&w[(size_t)(k0 + kl2) * 768 + bn + nl]);
        *reinterpret_cast<float4*>(&Bs[kl2 + 16][nl]) = ld4(&w[(size_t)(k0 + kl2 + 16) * 768 + bn + nl]);
        __syncthreads();
#pragma unroll
        for (int kk = 0; kk < 32; ++kk) {
            const float4 a = ld4(&As[kk][tm * 4]);
            const float4 bb = ld4(&Bs[kk][tn * 4]);
            const float av[4] = {a.x, a.y, a.z, a.w};
            const float bv[4] = {bb.x, bb.y, bb.z, bb.w};
#pragma unroll
            for (int mi = 0; mi < 4; ++mi)
#pragma unroll
                for (int ni = 0; ni < 4; ++ni) acc[mi][ni] += av[mi] * bv[ni];
        }
        __syncthreads();
    }
    // epilogue: col tile is entirely within one section (q/k/v) and one head
    const int sec = bn >> 8;
    const int h_ = (bn & 255) >> 6;
    float* dst = sec == 0 ? q : (sec == 1 ? k : v);
#pragma unroll
    for (int mi = 0; mi < 4; ++mi) {
        const int row = bm + tm * 4 + mi;
        const int b_ = row >> 11, n_ = row & 2047;
        float4 o = {acc[mi][0], acc[mi][1], acc[mi][2], acc[mi][3]};
        *reinterpret_cast<float4*>(&dst[(((size_t)b_ * Hh + h_) * Nn + n_) * DHh + tn * 4]) = o;
    }
}

// ---------------------------------------------------------------------------
// K2: qproj[bh,n,c] = q[bh,n,:] @ w_e1[0:64,:] + b_e1   (c padded to 276, pad=0)
//     kproj[bh,n,c] = k[bh,n,:] @ w_e1[64:128,:]
// grid (5, 32, 16=bh*2), block 256
// ---------------------------------------------------------------------------
__global__ __launch_bounds__(256) void k_proj(const float* __restrict__ q,
                                              const float* __restrict__ k,
                                              const float* __restrict__ w_e1,
                                              const float* __restrict__ b_e1,
                                              float* __restrict__ qproj,
                                              float* __restrict__ kproj) {
    __shared__ float As[32][68];
    __shared__ float Bs[32][68];
    const int t = threadIdx.x;
    const int z = blockIdx.z;
    const int which = z & 1;       // 0 = q, 1 = k
    const int bh = z >> 1;         // 0..7
    const float* src = which ? k : q;
    const float* wsl = w_e1 + (which ? 64 * CE : 0);
    float* dst = which ? kproj : qproj;
    const int c0 = blockIdx.x * 64;
    const int n0 = blockIdx.y * 64;
    const int tn = t & 15;   // n sub-tile
    const int tc = t >> 4;   // c sub-tile
    const int ml = t >> 3, kl = (t & 7) << 2;
    const int kl2 = t >> 4, nl = (t & 15) << 2;
    float acc[4][4] = {};    // [ni][ci]
    for (int k0 = 0; k0 < 64; k0 += 32) {
        float4 a0 = ld4(&src[((size_t)bh * Nn + n0 + ml) * 64 + k0 + kl]);
        float4 a1 = ld4(&src[((size_t)bh * Nn + n0 + ml + 32) * 64 + k0 + kl]);
        As[kl + 0][ml] = a0.x; As[kl + 1][ml] = a0.y; As[kl + 2][ml] = a0.z; As[kl + 3][ml] = a0.w;
        As[kl + 0][ml + 32] = a1.x; As[kl + 1][ml + 32] = a1.y; As[kl + 2][ml + 32] = a1.z; As[kl + 3][ml + 32] = a1.w;
#pragma unroll
        for (int e = 0; e < 4; ++e) {
            const int c = c0 + nl + e;
            Bs[kl2][nl + e]      = (c < CE) ? wsl[(size_t)(k0 + kl2) * CE + c] : 0.f;
            Bs[kl2 + 16][nl + e] = (c < CE) ? wsl[(size_t)(k0 + kl2 + 16) * CE + c] : 0.f;
        }
        __syncthreads();
#pragma unroll
        for (int kk = 0; kk < 32; ++kk) {
            const float4 a = ld4(&As[kk][tn * 4]);
            const float4 bb = ld4(&Bs[kk][tc * 4]);
            const float av[4] = {a.x, a.y, a.z, a.w};
            const float bv[4] = {bb.x, bb.y, bb.z, bb.w};
#pragma unroll
            for (int ni = 0; ni < 4; ++ni)
#pragma unroll
                for (int ci = 0; ci < 4; ++ci) acc[ni][ci] += av[ni] * bv[ci];
        }
        __syncthreads();
    }
    const int cbase = c0 + tc * 4;
    if (cbase < CEP) {
        float bias[4];
#pragma unroll
        for (int ci = 0; ci < 4; ++ci) {
            const int c = cbase + ci;
            bias[ci] = (!which && c < CE) ? b_e1[c] : 0.f;
        }
#pragma unroll
        for (int ni = 0; ni < 4; ++ni) {
            const int n = n0 + tn * 4 + ni;
            float4 o = {acc[ni][0] + bias[0], acc[ni][1] + bias[1],
                        acc[ni][2] + bias[2], acc[ni][3] + bias[3]};
            *reinterpret_cast<float4*>(&dst[(size_t)(bh * Nn + n) * CEP + cbase]) = o;
        }
    }
}

// ---------------------------------------------------------------------------
// K3: edge kernel. block = (b,h, 32 query nodes); 256 threads; thread owns
//     4 edges (4 consecutive i, 1 j). grid 512 = B*H*(N/32).
// ---------------------------------------------------------------------------
__global__ __launch_bounds__(256, 2) void k_edge(
    const float* __restrict__ coors, const int* __restrict__ nbhd,
    const float* __restrict__ qproj, const float* __restrict__ kproj,
    const float* __restrict__ v, const float* __restrict__ basis,
    const float* __restrict__ w_e1, const float* __restrict__ w_e2, const float* __restrict__ b_e2,
    const float* __restrict__ w_a1, const float* __restrict__ b_a1,
    const float* __restrict__ w_a2, const float* __restrict__ b_a2,
    const float* __restrict__ w_c1, const float* __restrict__ b_c1,
    const float* __restrict__ w_c2, const float* __restrict__ b_c2,
    float* __restrict__ out_tmp, float* __restrict__ coors_out) {

    __shared__ float s_we2[CEP][16];
    __shared__ float s_we1r[9][CEP];
    __shared__ float s_wa1[16][64];
    __shared__ float s_wc1[16][64];
    __shared__ float s_wa2[64], s_wc2[64], s_ba1[64], s_bc1[64], s_be2[16];
    __shared__ float s_attn[32][33];
    __shared__ int s_nbr[32][33];

    const int t = threadIdx.x;
    const int blk = blockIdx.x;
    const int ichunk = blk & 63;
    const int bh = blk >> 6;
    const int h = bh & 3, b = bh >> 2;
    const int ibase = ichunk * 32;
    const int j = t & 31;
    const int ig = t >> 5;
    const int i0 = ibase + ig * 4;

    for (int x = t; x < CEP * 16; x += 256) {
        const int c = x >> 4, mm = x & 15;
        s_we2[c][mm] = (c < CE) ? w_e2[c * 16 + mm] : 0.f;
    }
    for (int x = t; x < 9 * CEP; x += 256) {
        const int r = x / CEP, c = x - r * CEP;
        s_we1r[r][c] = (c < CE) ? w_e1[(128 + r) * CE + c] : 0.f;
    }
    for (int x = t; x < 1024; x += 256) {
        const int mm = x >> 6, u = x & 63;
        s_wa1[mm][u] = w_a1[x];
        s_wc1[mm][u] = w_c1[x];
    }
    if (t < 64) { s_wa2[t] = w_a2[t]; s_wc2[t] = w_c2[t]; s_ba1[t] = b_a1[t]; s_bc1[t] = b_c1[t]; }
    if (t < 16) s_be2[t] = b_e2[t];
    __syncthreads();

    // per-edge setup: neighbor index + fourier-encoded squared distance
    int nbr[4];
    float renc[4][9];
#pragma unroll
    for (int ii = 0; ii < 4; ++ii) {
        const int i = i0 + ii;
        const int nb = nbhd[((size_t)b * Nn + i) * Jj + j];
        nbr[ii] = nb;
        const float* cp = &coors[((size_t)b * Nn + i) * 3];
        const float* np = &coors[((size_t)b * Nn + nb) * 3];
        const float dx = cp[0] - np[0], dy = cp[1] - np[1], dz = cp[2] - np[2];
        const float d2 = dx * dx + dy * dy + dz * dz;
        float s = 1.f;
#pragma unroll
        for (int f = 0; f < 4; ++f) {
            const float xs = d2 * s;
            renc[ii][f] = sinf(xs);
            renc[ii][4 + f] = cosf(xs);
            s *= 0.5f;
        }
        renc[ii][8] = d2;
    }

    const float* qrow0 = qproj + (size_t)(bh * Nn + i0) * CEP;
    const float* krow[4];
#pragma unroll
    for (int ii = 0; ii < 4; ++ii) krow[ii] = kproj + (size_t)(bh * Nn + nbr[ii]) * CEP;

    // main loop: m[ii][:] = sum_c relu(qp+kp+rp) * w_e2[c][:]
    float m[4][16] = {};
    for (int c4 = 0; c4 < CEP; c4 += 4) {
        float4 wr[9];
#pragma unroll
        for (int r = 0; r < 9; ++r) wr[r] = ld4(&s_we1r[r][c4]);
        float hc[4][4];
#pragma unroll
        for (int ii = 0; ii < 4; ++ii) {
            const float4 qp = ld4(qrow0 + (size_t)ii * CEP + c4);
            const float4 kp = ld4(krow[ii] + c4);
            float rx = 0.f, ry = 0.f, rz = 0.f, rw = 0.f;
#pragma unroll
            for (int r = 0; r < 9; ++r) {
                const float e = renc[ii][r];
                rx += e * wr[r].x; ry += e * wr[r].y; rz += e * wr[r].z; rw += e * wr[r].w;
            }
            hc[ii][0] = fmaxf(qp.x + kp.x + rx, 0.f);
            hc[ii][1] = fmaxf(qp.y + kp.y + ry, 0.f);
            hc[ii][2] = fmaxf(qp.z + kp.z + rz, 0.f);
            hc[ii][3] = fmaxf(qp.w + kp.w + rw, 0.f);
        }
#pragma unroll
        for (int cc = 0; cc < 4; ++cc) {
            const float4 w0 = ld4(&s_we2[c4 + cc][0]);
            const float4 w1 = ld4(&s_we2[c4 + cc][4]);
            const float4 w2 = ld4(&s_we2[c4 + cc][8]);
            const float4 w3 = ld4(&s_we2[c4 + cc][12]);
#pragma unroll
            for (int ii = 0; ii < 4; ++ii) {
                const float hv = hc[ii][cc];
                m[ii][0] += hv * w0.x; m[ii][1] += hv * w0.y; m[ii][2] += hv * w0.z; m[ii][3] += hv * w0.w;
                m[ii][4] += hv * w1.x; m[ii][5] += hv * w1.y; m[ii][6] += hv * w1.z; m[ii][7] += hv * w1.w;
                m[ii][8] += hv * w2.x; m[ii][9] += hv * w2.y; m[ii][10] += hv * w2.z; m[ii][11] += hv * w2.w;
                m[ii][12] += hv * w3.x; m[ii][13] += hv * w3.y; m[ii][14] += hv * w3.z; m[ii][15] += hv * w3.w;
            }
        }
    }
#pragma unroll
    for (int ii = 0; ii < 4; ++ii)
#pragma unroll
        for (int mm = 0; mm < 16; ++mm) m[ii][mm] = fmaxf(m[ii][mm] + s_be2[mm], 0.f);

    // a/c heads: sim = relu(m@w_a1+b_a1)@w_a2 + b_a2 ; cw likewise with c-weights
    float sim[4], cw[4];
    const float ba2v = b_a2[0], bc2v = b_c2[0];
#pragma unroll
    for (int ii = 0; ii < 4; ++ii) { sim[ii] = ba2v; cw[ii] = bc2v; }
    for (int u4 = 0; u4 < 64; u4 += 4) {
        const float4 ba = ld4(&s_ba1[u4]);
        const float4 bc = ld4(&s_bc1[u4]);
        float4 ta[4], tc[4];
#pragma unroll
        for (int ii = 0; ii < 4; ++ii) { ta[ii] = ba; tc[ii] = bc; }
#pragma unroll
        for (int mm = 0; mm < 16; ++mm) {
            const float4 wa = ld4(&s_wa1[mm][u4]);
            const float4 wc = ld4(&s_wc1[mm][u4]);
#pragma unroll
            for (int ii = 0; ii < 4; ++ii) {
                const float mv = m[ii][mm];
                ta[ii].x += mv * wa.x; ta[ii].y += mv * wa.y; ta[ii].z += mv * wa.z; ta[ii].w += mv * wa.w;
                tc[ii].x += mv * wc.x; tc[ii].y += mv * wc.y; tc[ii].z += mv * wc.z; tc[ii].w += mv * wc.w;
            }
        }
        const float4 a2 = ld4(&s_wa2[u4]);
        const float4 c2 = ld4(&s_wc2[u4]);
#pragma unroll
        for (int ii = 0; ii < 4; ++ii) {
            sim[ii] += fmaxf(ta[ii].x, 0.f) * a2.x + fmaxf(ta[ii].y, 0.f) * a2.y +
                       fmaxf(ta[ii].z, 0.f) * a2.z + fmaxf(ta[ii].w, 0.f) * a2.w;
            cw[ii] += fmaxf(tc[ii].x, 0.f) * c2.x + fmaxf(tc[ii].y, 0.f) * c2.y +
                      fmaxf(tc[ii].z, 0.f) * c2.z + fmaxf(tc[ii].w, 0.f) * c2.w;
        }
    }

    // coors_out: sum over j (32 lanes) then atomic add across (h-)blocks
#pragma unroll
    for (int ii = 0; ii < 4; ++ii) {
        const int i = i0 + ii;
        const float* bp = basis + ((size_t)(b * Nn + i) * Nn + nbr[ii]) * 3;
        float px = cw[ii] * bp[0], py = cw[ii] * bp[1], pz = cw[ii] * bp[2];
#pragma unroll
        for (int off = 16; off >= 1; off >>= 1) {
            px += __shfl_xor(px, off, 32);
            py += __shfl_xor(py, off, 32);
            pz += __shfl_xor(pz, off, 32);
        }
        if (j == 0) {
            float* co = &coors_out[((size_t)b * Nn + i) * 3];
            atomicAdd(&co[0], px);
            atomicAdd(&co[1], py);
            atomicAdd(&co[2], pz);
        }
    }

    // softmax over j within each 32-lane group
    float attn[4];
#pragma unroll
    for (int ii = 0; ii < 4; ++ii) {
        float mx = sim[ii];
#pragma unroll
        for (int off = 16; off >= 1; off >>= 1) mx = fmaxf(mx, __shfl_xor(mx, off, 32));
        const float e = __expf(sim[ii] - mx);
        float sm = e;
#pragma unroll
        for (int off = 16; off >= 1; off >>= 1) sm += __shfl_xor(sm, off, 32);
        attn[ii] = e / sm;
    }

#pragma unroll
    for (int ii = 0; ii < 4; ++ii) {
        s_attn[ig * 4 + ii][j] = attn[ii];
        s_nbr[ig * 4 + ii][j] = nbr[ii];
    }
    __syncthreads();

    // attn @ v_nb: thread -> (i_local = t/8, 8 d's)
    const int il = t >> 3;
    const int d0 = (t & 7) << 3;
    const float* vb = v + (size_t)bh * Nn * DHh;
    float acc8[8] = {};
#pragma unroll 4
    for (int jj = 0; jj < 32; ++jj) {
        const float a = s_attn[il][jj];
        const int nb = s_nbr[il][jj];
        const float* vr = vb + (size_t)nb * DHh + d0;
        const float4 v0 = ld4(vr);
        const float4 v1 = ld4(vr + 4);
        acc8[0] += a * v0.x; acc8[1] += a * v0.y; acc8[2] += a * v0.z; acc8[3] += a * v0.w;
        acc8[4] += a * v1.x; acc8[5] += a * v1.y; acc8[6] += a * v1.z; acc8[7] += a * v1.w;
    }
    const int gi = ibase + il;
    float* op = out_tmp + ((size_t)(b * Nn + gi) * Hh + h) * DHh + d0;
    float4 o0 = {acc8[0], acc8[1], acc8[2], acc8[3]};
    float4 o1 = {acc8[4], acc8[5], acc8[6], acc8[7]};
    *reinterpret_cast<float4*>(op) = o0;
    *reinterpret_cast<float4*>(op + 4) = o1;
}

// ---------------------------------------------------------------------------
// K4: out = tmp(4096x256) @ w_out(256x256) + b_out
// grid (4, 64), block 256
// ---------------------------------------------------------------------------
__global__ __launch_bounds__(256) void k_out(const float* __restrict__ tmp,
                                             const float* __restrict__ w,
                                             const float* __restrict__ bias,
                                             float* __restrict__ outp) {
    __shared__ float As[32][68];
    __shared__ float Bs[32][68];
    const int t = threadIdx.x;
    const int bn = blockIdx.x * 64;
    const int bm = blockIdx.y * 64;
    const int tn = t & 15, tm = t >> 4;
    const int ml = t >> 3, kl = (t & 7) << 2;
    const int kl2 = t >> 4, nl = (t & 15) << 2;
    float acc[4][4] = {};
    for (int k0 = 0; k0 < 256; k0 += 32) {
        float4 a0 = ld4(&tmp[(size_t)(bm + ml) * 256 + k0 + kl]);
        float4 a1 = ld4(&tmp[(size_t)(bm + ml + 32) * 256 + k0 + kl]);
        As[kl + 0][ml] = a0.x; As[kl + 1][ml] = a0.y; As[kl + 2][ml] = a0.z; As[kl + 3][ml] = a0.w;
        As[kl + 0][ml + 32] = a1.x; As[kl + 1][ml + 32] = a1.y; As[kl + 2][ml + 32] = a1.z; As[kl + 3][ml + 32] = a1.w;
        *reinterpret_cast<float4*>(&Bs[kl2][nl])      = ld4(&w[(size_t)(k0 + kl2) * 256 + bn + nl]);
        *reinterpret_cast<float4*>(&Bs[kl2 + 16][nl]) = ld4(&w[(size_t)(k0 + kl2 + 16) * 256 + bn + nl]);
        __syncthreads();
#pragma unroll
        for (int kk = 0; kk < 32; ++kk) {
            const float4 a = ld4(&As[kk][tm * 4]);
            const float4 bb = ld4(&Bs[kk][tn * 4]);
            const float av[4] = {a.x, a.y, a.z, a.w};
            const float bv[4] = {bb.x, bb.y, bb.z, bb.w};
#pragma unroll
            for (int mi = 0; mi < 4; ++mi)
#pragma unroll
                for (int ni = 0; ni < 4; ++ni) acc[mi][ni] += av[mi] * bv[ni];
        }
        __syncthreads();
    }
    const int c = bn + tn * 4;
    const float4 bv4 = ld4(&bias[c]);
#pragma unroll
    for (int mi = 0; mi < 4; ++mi) {
        const int row = bm + tm * 4 + mi;
        float4 o = {acc[mi][0] + bv4.x, acc[mi][1] + bv4.y, acc[mi][2] + bv4.z, acc[mi][3] + bv4.w};
        *reinterpret_cast<float4*>(&outp[(size_t)row * 256 + c]) = o;
    }
}

// ---------------------------------------------------------------------------
extern "C" void kernel_launch(void* const* d_in, const int* in_sizes, int n_in,
                              void* d_out, int out_size, void* d_ws, size_t ws_size,
                              hipStream_t stream) {
    const float* feats = (const float*)d_in[0];
    const float* coors = (const float*)d_in[1];
    const float* basis = (const float*)d_in[2];
    const int* nbhd = (const int*)d_in[3];
    const float* w_qkv = (const float*)d_in[4];
    const float* w_out = (const float*)d_in[5];
    const float* b_out = (const float*)d_in[6];
    const float* w_e1 = (const float*)d_in[7];
    const float* b_e1 = (const float*)d_in[8];
    const float* w_e2 = (const float*)d_in[9];
    const float* b_e2 = (const float*)d_in[10];
    const float* w_a1 = (const float*)d_in[11];
    const float* b_a1 = (const float*)d_in[12];
    const float* w_a2 = (const float*)d_in[13];
    const float* b_a2 = (const float*)d_in[14];
    const float* w_c1 = (const float*)d_in[15];
    const float* b_c1 = (const float*)d_in[16];
    const float* w_c2 = (const float*)d_in[17];
    const float* b_c2 = (const float*)d_in[18];

    float* ws = (float*)d_ws;
    float* q = ws;                                     // 1,048,576
    float* k = q + (size_t)Bsz * Hh * Nn * DHh;        // 1,048,576
    float* v = k + (size_t)Bsz * Hh * Nn * DHh;        // 1,048,576
    float* qproj = v + (size_t)Bsz * Hh * Nn * DHh;    // 8*2048*276 = 4,521,984
    float* kproj = qproj + (size_t)Bsz * Hh * Nn * CEP;
    float* tmp = kproj + (size_t)Bsz * Hh * Nn * CEP;  // 1,048,576

    float* outp = (float*)d_out;
    float* coors_out = outp + (size_t)Bsz * Nn * Dd;

    hipLaunchKernelGGL(k_zero, dim3(48), dim3(256), 0, stream, coors_out, Bsz * Nn * 3);
    hipLaunchKernelGGL(k_qkv, dim3(12, 64), dim3(256), 0, stream, feats, w_qkv, q, k, v);
    hipLaunchKernelGGL(k_proj, dim3(5, 32, 16), dim3(256), 0, stream, q, k, w_e1, b_e1, qproj, kproj);
    hipLaunchKernelGGL(k_edge, dim3(512), dim3(256), 0, stream,
                       coors, nbhd, qproj, kproj, v, basis,
                       w_e1, w_e2, b_e2, w_a1, b_a1, w_a2, b_a2,
                       w_c1, b_c1, w_c2, b_c2, tmp, coors_out);
    hipLaunchKernelGGL(k_out, dim3(4, 64), dim3(256), 0, stream, tmp, w_out, b_out, outp);
}